// Round 7
// baseline (197.915 us; speedup 1.0000x reference)
//
#include <hip/hip_runtime.h>

// Trilinear interp of [64,64,64,64] fp32 volume at 200k points.
// R13: staged family (verified R9 skeleton) with 8^3 buckets to cut halo
// over-fetch: ((B+1)/B)^3 = 1.42x at B=8 vs 1.95x at B=4 -> staged bytes
// 131 MB -> ~96 MB. An 8^3 halo tile (9^3 voxels x 256B = 186 KB) doesn't
// fit LDS, so each bucket is served by 4 channel-split blocks (4 of 16
// float4 channels each): tile = 729 vox x 64B = 46 KB -> 3 blocks/CU.
// Evidence basis: R8/R11 (overlap levers) neutral -> staged gather is
// issued-bytes-bound; R7/R12 (direct) pinned at ~49us by scattered-request
// throughput -> direct family closed. Poison discipline = R9/R11's
// verified pattern: unconditional slot loads, GATED consumption, scalar
// scatter.

#define NB8     512           // 8^3 grid of 8^3-voxel buckets
#define CAP8    640           // mean occupancy 390, +12 sigma
#define OVCAP   8192
#define TILE8_F4 2944         // 46 used chunks x 64 f4 (729 vox x 4 f4 = 2916)
#define NGB     2048          // 4 channel-split blocks per bucket

typedef float __attribute__((ext_vector_type(4))) fx4;

#define GLOBAL_AS __attribute__((address_space(1)))
#define LDS_AS    __attribute__((address_space(3)))

__device__ __forceinline__ void async_copy16(const float4* g, float4* l) {
    __builtin_amdgcn_global_load_lds(
        (const GLOBAL_AS unsigned int*)(const void*)g,
        (LDS_AS unsigned int*)(void*)l, 16, 0, 0);
}

__device__ __forceinline__ float4 f4mul(float4 a, float s) {
    return make_float4(a.x * s, a.y * s, a.z * s, a.w * s);
}
__device__ __forceinline__ float4 f4fma(float4 a, float s, float4 acc) {
    return make_float4(fmaf(a.x, s, acc.x), fmaf(a.y, s, acc.y),
                       fmaf(a.z, s, acc.z), fmaf(a.w, s, acc.w));
}

__global__ __launch_bounds__(256) void scatter_kernel(
    const float* __restrict__ coords, int* __restrict__ counts,
    float4* __restrict__ buckets, float4* __restrict__ overflow, int n)
{
    int p = blockIdx.x * 256 + threadIdx.x;
    if (p >= n) return;
    float xs = coords[3 * p + 0] * 0.5f;
    float ys = coords[3 * p + 1] * 0.5f;
    float zs = coords[3 * p + 2] * 0.5f;
    int vx = (int)floorf(xs), vy = (int)floorf(ys), vz = (int)floorf(zs);
    int bucket = ((vx >> 3) << 6) | ((vy >> 3) << 3) | (vz >> 3);
    int slot = atomicAdd(&counts[bucket], 1);
    float4 v = make_float4(xs, ys, zs, __int_as_float(p));
    if (slot < CAP8) {
        buckets[bucket * CAP8 + slot] = v;
    } else {
        int o = atomicAdd(&counts[NB8], 1);
        if (o < OVCAP) overflow[o] = v;
    }
}

// Pure-LDS trilinear lerp over this block's 4 float4 channels.
// cur = 9^3 voxels x 4 float4, index (lx*81+ly*9+lz)*4 + cvec.
__device__ __forceinline__ void lerp_lds_q(
    const float4* __restrict__ cur, float4 cs,
    int bx0, int by0, int bz0, int cvec, int chbase,
    float* __restrict__ out)
{
    float x = cs.x, y = cs.y, z = cs.z;
    int p = __float_as_int(cs.w);

    float fx1 = floorf(x), fx2 = fminf(ceilf(x), 63.0f);
    float fy1 = floorf(y), fy2 = fminf(ceilf(y), 63.0f);
    float fz1 = floorf(z), fz2 = fminf(ceilf(z), 63.0f);

    int ax1 = ((int)fx1 - bx0) * 81, ax2 = ((int)fx2 - bx0) * 81;
    int ay1 = ((int)fy1 - by0) * 9,  ay2 = ((int)fy2 - by0) * 9;
    int lz1 = (int)fz1 - bz0,        lz2 = (int)fz2 - bz0;

    float wx = x - fx1, wxc = fx2 - x;
    float wy = y - fy1, wyc = fy2 - y;
    float wz = z - fz1, wzc = fz2 - z;

    // z1 plane
    float4 q11 = cur[((ax1 + ay1 + lz1) << 2) + cvec];
    float4 q21 = cur[((ax2 + ay1 + lz1) << 2) + cvec];
    float4 q12 = cur[((ax1 + ay2 + lz1) << 2) + cvec];
    float4 q22 = cur[((ax2 + ay2 + lz1) << 2) + cvec];
    float4 ly1v = f4fma(f4fma(q22, wx, f4mul(q12, wxc)), wy,
                        f4mul(f4fma(q21, wx, f4mul(q11, wxc)), wyc));
    // z2 plane
    q11 = cur[((ax1 + ay1 + lz2) << 2) + cvec];
    q21 = cur[((ax2 + ay1 + lz2) << 2) + cvec];
    q12 = cur[((ax1 + ay2 + lz2) << 2) + cvec];
    q22 = cur[((ax2 + ay2 + lz2) << 2) + cvec];
    float4 ly2v = f4fma(f4fma(q22, wx, f4mul(q12, wxc)), wy,
                        f4mul(f4fma(q21, wx, f4mul(q11, wxc)), wyc));

    float4 res = f4fma(ly2v, wz, f4mul(ly1v, wzc));
    fx4 r; r.x = res.x; r.y = res.y; r.z = res.z; r.w = res.w;
    __builtin_nontemporal_store(r, (fx4*)out + (p << 4) + chbase + cvec);
}

__device__ __forceinline__ void lerp_global_store(
    const float4* __restrict__ imgv, float4 cs, int cvec,
    float* __restrict__ out)
{
    float x = cs.x, y = cs.y, z = cs.z;
    int p = __float_as_int(cs.w);

    float fx1 = floorf(x), fx2 = fminf(ceilf(x), 63.0f);
    float fy1 = floorf(y), fy2 = fminf(ceilf(y), 63.0f);
    float fz1 = floorf(z), fz2 = fminf(ceilf(z), 63.0f);

    int bx1 = ((int)fx1) << 12, bx2 = ((int)fx2) << 12;
    int by1 = ((int)fy1) << 6,  by2 = ((int)fy2) << 6;
    int iz1 = (int)fz1, iz2 = (int)fz2;

    float wx = x - fx1, wxc = fx2 - x;
    float wy = y - fy1, wyc = fy2 - y;
    float wz = z - fz1, wzc = fz2 - z;

    float4 q11 = imgv[((bx1 + by1 + iz1) << 4) + cvec];
    float4 q21 = imgv[((bx2 + by1 + iz1) << 4) + cvec];
    float4 q12 = imgv[((bx1 + by2 + iz1) << 4) + cvec];
    float4 q22 = imgv[((bx2 + by2 + iz1) << 4) + cvec];
    float4 ly1v = f4fma(f4fma(q22, wx, f4mul(q12, wxc)), wy,
                        f4mul(f4fma(q21, wx, f4mul(q11, wxc)), wyc));
    q11 = imgv[((bx1 + by1 + iz2) << 4) + cvec];
    q21 = imgv[((bx2 + by1 + iz2) << 4) + cvec];
    q12 = imgv[((bx1 + by2 + iz2) << 4) + cvec];
    q22 = imgv[((bx2 + by2 + iz2) << 4) + cvec];
    float4 ly2v = f4fma(f4fma(q22, wx, f4mul(q12, wxc)), wy,
                        f4mul(f4fma(q21, wx, f4mul(q11, wxc)), wyc));

    float4 res = f4fma(ly2v, wz, f4mul(ly1v, wzc));
    fx4 r; r.x = res.x; r.y = res.y; r.z = res.z; r.w = res.w;
    __builtin_nontemporal_store(r, (fx4*)out + (p << 4) + cvec);
}

__global__ __launch_bounds__(512, 4) void gather_kernel(
    const float* __restrict__ img, const int* __restrict__ counts,
    const float4* __restrict__ buckets, const float4* __restrict__ overflow,
    float* __restrict__ out)
{
    const float4* __restrict__ imgv = (const float4*)img;

    if (blockIdx.x < NGB) {
        __shared__ float4 tile[TILE8_F4];   // 46 KB: 729 vox x 4 float4
        int cvec = threadIdx.x & 3;         // float4 channel within quarter
        int grp  = threadIdx.x >> 2;        // 0..127 point group
        int wv   = threadIdx.x >> 6;        // wave 0..7
        int lane = threadIdx.x & 63;

        // XCD swizzle: 8 XCDs x 256 contiguous seq; the 4 splits of a
        // bucket + z-neighbor buckets share an XCD -> DMA + list reads L2-hit.
        int seq    = (blockIdx.x & 7) * 256 + (blockIdx.x >> 3);
        int bucket = seq >> 2;
        int split  = seq & 3;
        int chbase = split << 2;            // float4 channel base 0/4/8/12
        int base   = bucket * CAP8;
        int bx0 = (bucket >> 6) << 3;
        int by0 = ((bucket >> 3) & 7) << 3;
        int bz0 = (bucket & 7) << 3;

        // --- prefetch (oldest vmem first): count + 3 slots per group ---
        int cnt = counts[bucket];                    // uniform
        float4 cs0 = buckets[base + grp];            // grp+256 <= 383 < CAP8:
        float4 cs1 = buckets[base + grp + 128];      // always in-bounds
        float4 cs2 = buckets[base + grp + 256];

        // --- stage 9^3 halo, this quarter's channels:
        //     46 chunks x 64 lanes x 16B = 46 KB (waves 0-6: 6 chunks, w7: 4)
        #pragma unroll
        for (int c = 0; c < 6; c++) {
            int chunk = wv * 6 + c;              // 0..47
            if (chunk < 46) {                    // wave-uniform guard
                int f = chunk * 64 + lane;       // 0..2943
                int tv = min(f >> 2, 728);       // voxel 0..728 (pad clamps)
                int ch = (f & 3) + chbase;
                int lx = tv / 81;
                int rem = tv - lx * 81;
                int ly = rem / 9;
                int lz = rem - ly * 9;
                int gx = min(bx0 + lx, 63);
                int gy = min(by0 + ly, 63);
                int gz = min(bz0 + lz, 63);
                const float4* src =
                    &imgv[(((((gx << 6) + gy) << 6) + gz) << 4) + ch];
                async_copy16(src, &tile[chunk * 64]);   // HW adds lane*16B
            }
        }
        cnt = min(cnt, CAP8);

        __syncthreads();   // vmcnt(0): all DMAs landed

        // Gated consumption (poison-safe, verified R9/R11 pattern).
        if (grp < cnt)
            lerp_lds_q(tile, cs0, bx0, by0, bz0, cvec, chbase, out);
        if (grp + 128 < cnt)
            lerp_lds_q(tile, cs1, bx0, by0, bz0, cvec, chbase, out);
        if (grp + 256 < cnt)
            lerp_lds_q(tile, cs2, bx0, by0, bz0, cvec, chbase, out);
        // residual (cnt > 384): rare at mean 390? no -- covers tail to 640
        for (int t = grp + 384; t < cnt; t += 128) {
            float4 cs = buckets[base + t];
            lerp_lds_q(tile, cs, bx0, by0, bz0, cvec, chbase, out);
        }
    } else {
        // overflow points (normally zero): direct global gather, full 16 ch
        int cvec = threadIdx.x & 15;
        int grp  = threadIdx.x >> 4;            // 0..31
        int ob = blockIdx.x - NGB;              // 0..31
        int cnt = min(counts[NB8], OVCAP);
        for (int i = (ob << 5) + grp; i < cnt; i += 32 * 32) {
            float4 cs = overflow[i];
            lerp_global_store(imgv, cs, cvec, out);
        }
    }
}

// Fallback (R1 kernel) if workspace too small.
__global__ __launch_bounds__(256) void trilerp_kernel(
    const float* __restrict__ img, const float* __restrict__ coords,
    float* __restrict__ out, int n_points)
{
    int tid = blockIdx.x * 256 + threadIdx.x;
    int p = tid >> 4;
    if (p >= n_points) return;
    int cvec = tid & 15;

    float x = coords[3 * p + 0] * 0.5f;
    float y = coords[3 * p + 1] * 0.5f;
    float z = coords[3 * p + 2] * 0.5f;

    float4 cs = make_float4(x, y, z, __int_as_float(p));
    lerp_global_store((const float4*)img, cs, cvec, out);
}

extern "C" void kernel_launch(void* const* d_in, const int* in_sizes, int n_in,
                              void* d_out, int out_size, void* d_ws, size_t ws_size,
                              hipStream_t stream) {
    const float* img    = (const float*)d_in[0];   // [1,64,64,64,64]
    const float* coords = (const float*)d_in[1];   // [1,N,3]
    float* out = (float*)d_out;                    // [1,N,64]
    int n = in_sizes[1] / 3;

    size_t counts_bytes  = 32768;                                   // padded
    size_t buckets_off   = counts_bytes;
    size_t buckets_bytes = (size_t)NB8 * CAP8 * sizeof(float4);     // 5.24 MB
    size_t overflow_off  = buckets_off + buckets_bytes;
    size_t need = overflow_off + (size_t)OVCAP * sizeof(float4);

    if (ws_size >= need) {
        int*    counts   = (int*)d_ws;
        float4* buckets  = (float4*)((char*)d_ws + buckets_off);
        float4* overflow = (float4*)((char*)d_ws + overflow_off);

        hipMemsetAsync(counts, 0, (NB8 + 1) * sizeof(int), stream);
        int pgrid = (n + 255) / 256;
        scatter_kernel<<<pgrid, 256, 0, stream>>>(coords, counts, buckets, overflow, n);
        gather_kernel<<<NGB + 32, 512, 0, stream>>>(img, counts, buckets, overflow, out);
    } else {
        int threads = n * 16;
        int grid = (threads + 255) / 256;
        trilerp_kernel<<<grid, 256, 0, stream>>>(img, coords, out, n);
    }
}

// Round 8
// 140.207 us; speedup vs baseline: 1.4116x; 1.4116x over previous
//
#include <hip/hip_runtime.h>

// Trilinear interp of [64,64,64,64] fp32 volume at 200k points.
// R14 = R9 verbatim (verified best, 139.7us). Session evidence:
//  - staged gather ~35us vs ~29us BW floor; overlap depth (R8), residency
//    (R11), and issued-bytes (R13 8^3) levers all measured NEUTRAL.
//  - direct gather pinned ~49us by scattered-request throughput (R7=R12).
//  - 8^3 scatter = 63.8us atomic serialization (R13) -> 4096 counters kept.
// Structure: 4096 blocks, one 4^3 bucket + 5^3 halo tile each, async
// global->LDS DMA, 512 threads (32 groups -> 2 gated compute iters at mean
// occupancy), counts+points prefetched before DMA issue so their latency
// hides under staging; post-barrier path is pure LDS+FMA+store.

#define NBUCK   4096          // 16^3 buckets of 4^3 voxels
#define CAP     128           // mean occupancy 48.8
#define OVCAP   8192
#define TILE_F4 2048          // 5^3 voxels * 16 float4 = 2000, padded to 2048

typedef float __attribute__((ext_vector_type(4))) fx4;

#define GLOBAL_AS __attribute__((address_space(1)))
#define LDS_AS    __attribute__((address_space(3)))

__device__ __forceinline__ void async_copy16(const float4* g, float4* l) {
    __builtin_amdgcn_global_load_lds(
        (const GLOBAL_AS unsigned int*)(const void*)g,
        (LDS_AS unsigned int*)(void*)l, 16, 0, 0);
}

__device__ __forceinline__ float4 f4mul(float4 a, float s) {
    return make_float4(a.x * s, a.y * s, a.z * s, a.w * s);
}
__device__ __forceinline__ float4 f4fma(float4 a, float s, float4 acc) {
    return make_float4(fmaf(a.x, s, acc.x), fmaf(a.y, s, acc.y),
                       fmaf(a.z, s, acc.z), fmaf(a.w, s, acc.w));
}

__global__ __launch_bounds__(256) void scatter_kernel(
    const float* __restrict__ coords, int* __restrict__ counts,
    float4* __restrict__ buckets, float4* __restrict__ overflow, int n)
{
    int p = blockIdx.x * 256 + threadIdx.x;
    if (p >= n) return;
    float xs = coords[3 * p + 0] * 0.5f;
    float ys = coords[3 * p + 1] * 0.5f;
    float zs = coords[3 * p + 2] * 0.5f;
    int vx = (int)floorf(xs), vy = (int)floorf(ys), vz = (int)floorf(zs);
    int bucket = ((vx >> 2) << 8) | ((vy >> 2) << 4) | (vz >> 2);
    int slot = atomicAdd(&counts[bucket], 1);
    float4 v = make_float4(xs, ys, zs, __int_as_float(p));
    if (slot < CAP) {
        buckets[bucket * CAP + slot] = v;
    } else {
        int o = atomicAdd(&counts[NBUCK], 1);
        if (o < OVCAP) overflow[o] = v;
    }
}

// Pure-LDS trilinear lerp for one point (cs holds bucket-local coords in
// .x/.y/.z and the point id bit-cast in .w). Two-plane evaluation keeps
// only 4 q registers live at a time.
__device__ __forceinline__ void lerp_lds(
    const float4* __restrict__ cur, float4 cs,
    int bx0, int by0, int bz0, int cvec, float* __restrict__ out)
{
    float x = cs.x, y = cs.y, z = cs.z;
    int p = __float_as_int(cs.w);

    float fx1 = floorf(x), fx2 = fminf(ceilf(x), 63.0f);
    float fy1 = floorf(y), fy2 = fminf(ceilf(y), 63.0f);
    float fz1 = floorf(z), fz2 = fminf(ceilf(z), 63.0f);

    int ax1 = ((int)fx1 - bx0) * 25, ax2 = ((int)fx2 - bx0) * 25;
    int ay1 = ((int)fy1 - by0) * 5,  ay2 = ((int)fy2 - by0) * 5;
    int lz1 = (int)fz1 - bz0,        lz2 = (int)fz2 - bz0;

    float wx = x - fx1, wxc = fx2 - x;
    float wy = y - fy1, wyc = fy2 - y;
    float wz = z - fz1, wzc = fz2 - z;

    // z1 plane
    float4 q11 = cur[((ax1 + ay1 + lz1) << 4) + cvec];
    float4 q21 = cur[((ax2 + ay1 + lz1) << 4) + cvec];
    float4 q12 = cur[((ax1 + ay2 + lz1) << 4) + cvec];
    float4 q22 = cur[((ax2 + ay2 + lz1) << 4) + cvec];
    float4 ly1v = f4fma(f4fma(q22, wx, f4mul(q12, wxc)), wy,
                        f4mul(f4fma(q21, wx, f4mul(q11, wxc)), wyc));
    // z2 plane
    q11 = cur[((ax1 + ay1 + lz2) << 4) + cvec];
    q21 = cur[((ax2 + ay1 + lz2) << 4) + cvec];
    q12 = cur[((ax1 + ay2 + lz2) << 4) + cvec];
    q22 = cur[((ax2 + ay2 + lz2) << 4) + cvec];
    float4 ly2v = f4fma(f4fma(q22, wx, f4mul(q12, wxc)), wy,
                        f4mul(f4fma(q21, wx, f4mul(q11, wxc)), wyc));

    float4 res = f4fma(ly2v, wz, f4mul(ly1v, wzc));
    fx4 r; r.x = res.x; r.y = res.y; r.z = res.z; r.w = res.w;
    __builtin_nontemporal_store(r, (fx4*)out + (p << 4) + cvec);
}

__device__ __forceinline__ void lerp_global_store(
    const float4* __restrict__ imgv, float4 cs, int cvec,
    float* __restrict__ out)
{
    float x = cs.x, y = cs.y, z = cs.z;
    int p = __float_as_int(cs.w);

    float fx1 = floorf(x), fx2 = fminf(ceilf(x), 63.0f);
    float fy1 = floorf(y), fy2 = fminf(ceilf(y), 63.0f);
    float fz1 = floorf(z), fz2 = fminf(ceilf(z), 63.0f);

    int bx1 = ((int)fx1) << 12, bx2 = ((int)fx2) << 12;
    int by1 = ((int)fy1) << 6,  by2 = ((int)fy2) << 6;
    int iz1 = (int)fz1, iz2 = (int)fz2;

    float wx = x - fx1, wxc = fx2 - x;
    float wy = y - fy1, wyc = fy2 - y;
    float wz = z - fz1, wzc = fz2 - z;

    float4 q11 = imgv[((bx1 + by1 + iz1) << 4) + cvec];
    float4 q21 = imgv[((bx2 + by1 + iz1) << 4) + cvec];
    float4 q12 = imgv[((bx1 + by2 + iz1) << 4) + cvec];
    float4 q22 = imgv[((bx2 + by2 + iz1) << 4) + cvec];
    float4 ly1v = f4fma(f4fma(q22, wx, f4mul(q12, wxc)), wy,
                        f4mul(f4fma(q21, wx, f4mul(q11, wxc)), wyc));
    q11 = imgv[((bx1 + by1 + iz2) << 4) + cvec];
    q21 = imgv[((bx2 + by1 + iz2) << 4) + cvec];
    q12 = imgv[((bx1 + by2 + iz2) << 4) + cvec];
    q22 = imgv[((bx2 + by2 + iz2) << 4) + cvec];
    float4 ly2v = f4fma(f4fma(q22, wx, f4mul(q12, wxc)), wy,
                        f4mul(f4fma(q21, wx, f4mul(q11, wxc)), wyc));

    float4 res = f4fma(ly2v, wz, f4mul(ly1v, wzc));
    fx4 r; r.x = res.x; r.y = res.y; r.z = res.z; r.w = res.w;
    __builtin_nontemporal_store(r, (fx4*)out + (p << 4) + cvec);
}

__global__ __launch_bounds__(512, 8) void gather_kernel(
    const float* __restrict__ img, const int* __restrict__ counts,
    const float4* __restrict__ buckets, const float4* __restrict__ overflow,
    float* __restrict__ out)
{
    const float4* __restrict__ imgv = (const float4*)img;
    int cvec = threadIdx.x & 15;
    int grp  = threadIdx.x >> 4;          // 0..31

    if (blockIdx.x < NBUCK) {
        __shared__ float4 tile[TILE_F4];   // 32 KB single buffer
        int wv   = threadIdx.x >> 6;       // wave 0..7
        int lane = threadIdx.x & 63;
        // XCD chunk swizzle: 8 XCDs x 512 contiguous buckets, z-fastest ->
        // concurrent blocks on one XCD are z-neighbors, halo re-reads L2-hit.
        int bucket = (blockIdx.x & 7) * 512 + (blockIdx.x >> 3);
        int bx0 = (bucket >> 8) << 2;
        int by0 = ((bucket >> 4) & 15) << 2;
        int bz0 = (bucket & 15) << 2;

        // --- prefetch (oldest vmem first): counts + 2 points per group ---
        int cnt = counts[bucket];                       // uniform
        float4 cs0 = buckets[bucket * CAP + grp];       // always in-bounds
        float4 cs1 = buckets[bucket * CAP + grp + 32];  // (CAP=128)

        // --- stage 5^3 halo: 8 waves x 4 chunks x 64 lanes x 16B = 32 KB ---
        #pragma unroll
        for (int c = 0; c < 4; c++) {
            int chunk = (wv << 2) + c;           // 0..31
            int f = chunk * 64 + lane;           // 0..2047
            int tv = min(f >> 4, 124);           // voxel 0..124 (pad clamps)
            int ch = f & 15;
            int lx = tv / 25;
            int rem = tv - lx * 25;
            int ly = rem / 5;
            int lz = rem - ly * 5;
            int gx = min(bx0 + lx, 63);
            int gy = min(by0 + ly, 63);
            int gz = min(bz0 + lz, 63);
            const float4* src = &imgv[(((((gx << 6) + gy) << 6) + gz) << 4) + ch];
            async_copy16(src, &tile[chunk * 64]);   // HW adds lane*16B
        }
        cnt = min(cnt, CAP);

        // First use of cs0/cs1 is below the barrier; the compiler's wait for
        // them is vmcnt(4) (DMAs are newer), so any pre-barrier setup and the
        // other waves' staging overlap the point-load latency.
        __syncthreads();   // vmcnt(0): all DMAs landed

        if (grp < cnt)      lerp_lds(tile, cs0, bx0, by0, bz0, cvec, out);
        if (grp + 32 < cnt) lerp_lds(tile, cs1, bx0, by0, bz0, cvec, out);
        // residual (cnt > 64): ~1.4% of buckets
        for (int t = grp + 64; t < cnt; t += 32) {
            float4 cs = buckets[bucket * CAP + t];
            lerp_lds(tile, cs, bx0, by0, bz0, cvec, out);
        }
    } else {
        // overflow points (normally zero): direct global gather
        int ob = blockIdx.x - NBUCK;            // 0..31
        int cnt = min(counts[NBUCK], OVCAP);
        for (int i = (ob << 5) + grp; i < cnt; i += 32 * 32) {
            float4 cs = overflow[i];
            lerp_global_store(imgv, cs, cvec, out);
        }
    }
}

// Fallback (R1 kernel) if workspace too small.
__global__ __launch_bounds__(256) void trilerp_kernel(
    const float* __restrict__ img, const float* __restrict__ coords,
    float* __restrict__ out, int n_points)
{
    int tid = blockIdx.x * 256 + threadIdx.x;
    int p = tid >> 4;
    if (p >= n_points) return;
    int cvec = tid & 15;

    float x = coords[3 * p + 0] * 0.5f;
    float y = coords[3 * p + 1] * 0.5f;
    float z = coords[3 * p + 2] * 0.5f;

    float4 cs = make_float4(x, y, z, __int_as_float(p));
    lerp_global_store((const float4*)img, cs, cvec, out);
}

extern "C" void kernel_launch(void* const* d_in, const int* in_sizes, int n_in,
                              void* d_out, int out_size, void* d_ws, size_t ws_size,
                              hipStream_t stream) {
    const float* img    = (const float*)d_in[0];   // [1,64,64,64,64]
    const float* coords = (const float*)d_in[1];   // [1,N,3]
    float* out = (float*)d_out;                    // [1,N,64]
    int n = in_sizes[1] / 3;

    size_t counts_bytes = 32768;                              // 4097 ints, padded
    size_t buckets_off  = counts_bytes;
    size_t buckets_bytes = (size_t)NBUCK * CAP * sizeof(float4);   // 8 MB
    size_t overflow_off = buckets_off + buckets_bytes;
    size_t need = overflow_off + (size_t)OVCAP * sizeof(float4);

    if (ws_size >= need) {
        int*    counts   = (int*)d_ws;
        float4* buckets  = (float4*)((char*)d_ws + buckets_off);
        float4* overflow = (float4*)((char*)d_ws + overflow_off);

        hipMemsetAsync(counts, 0, (NBUCK + 1) * sizeof(int), stream);
        int pgrid = (n + 255) / 256;
        scatter_kernel<<<pgrid, 256, 0, stream>>>(coords, counts, buckets, overflow, n);
        gather_kernel<<<NBUCK + 32, 512, 0, stream>>>(img, counts, buckets, overflow, out);
    } else {
        int threads = n * 16;
        int grid = (threads + 255) / 256;
        trilerp_kernel<<<grid, 256, 0, stream>>>(img, coords, out, n);
    }
}